// Round 2
// baseline (3200.174 us; speedup 1.0000x reference)
//
#include <hip/hip_runtime.h>
#include <math.h>

#define BS   2048
#define SEQ  50
#define NPOS (BS * SEQ)

__device__ __forceinline__ float sigf(float x) { return 1.0f / (1.0f + __expf(-x)); }
__device__ __forceinline__ float tanhfast(float x) {
    float e = __expf(2.0f * x);
    return 1.0f - 2.0f / (e + 1.0f);
}

// ---------------------------------------------------------------------------
// Kernel A: edge fusion + masked multi-head attention -> ctx[BS][SEQ][64]
// block = 64 threads (1 wave); lane = output channel o; Wq/Wv rows in VGPRs.
// ---------------------------------------------------------------------------
__global__ __launch_bounds__(64) void edge_attn_ctx(
    const float* __restrict__ seqs,   // [BS,SEQ,3,3,6]
    const float* __restrict__ ets,    // [BS,SEQ,3,3,4]
    const int*   __restrict__ masks,  // [BS,SEQ,3,3]
    const float* __restrict__ Wf, const float* __restrict__ bf,  // [64,19],[64]
    const float* __restrict__ Wk, const float* __restrict__ bk,  // [64,6],[64]
    const float* __restrict__ Wq, const float* __restrict__ bq,  // [64,64],[64]
    const float* __restrict__ Wv, const float* __restrict__ bv,  // [64,64],[64]
    float* __restrict__ ctx)          // [BS,SEQ,64]
{
    const int o = threadIdx.x;

    // Register-cache the per-channel weight rows (once per block).
    float wq[64], wv[64], wf[19], wk[6];
    {
        const float4* qp = (const float4*)&Wq[o * 64];
        const float4* vp = (const float4*)&Wv[o * 64];
        #pragma unroll
        for (int k = 0; k < 16; ++k) {
            float4 a = qp[k];
            wq[k*4+0] = a.x; wq[k*4+1] = a.y; wq[k*4+2] = a.z; wq[k*4+3] = a.w;
            float4 b = vp[k];
            wv[k*4+0] = b.x; wv[k*4+1] = b.y; wv[k*4+2] = b.z; wv[k*4+3] = b.w;
        }
        #pragma unroll
        for (int k = 0; k < 19; ++k) wf[k] = Wf[o * 19 + k];
        #pragma unroll
        for (int k = 0; k < 6; ++k)  wk[k] = Wk[o * 6 + k];
    }
    const float bfr = bf[o], bkr = bk[o], bqr = bq[o], bvr = bv[o];

    __shared__ float s_seq[54];
    __shared__ float s_et[36];
    __shared__ int   s_mask[9];
    __shared__ float s_edge[9 * 64];

    for (int p = blockIdx.x; p < NPOS; p += gridDim.x) {
        if (o < 54) s_seq[o]  = seqs[p * 54 + o];
        if (o < 36) s_et[o]   = ets[p * 36 + o];
        if (o < 9)  s_mask[o] = masks[p * 9 + o];
        __syncthreads();

        // edge_info[e][o]: fused 19-dot; eye(9) concat collapses to wf[10+e].
        #pragma unroll
        for (int e = 0; e < 9; ++e) {
            float v = bfr + wf[10 + e];
            #pragma unroll
            for (int r = 0; r < 6; ++r) v = fmaf(s_seq[e * 6 + r], wf[r], v);
            #pragma unroll
            for (int t = 0; t < 4; ++t) v = fmaf(s_et[e * 4 + t], wf[6 + t], v);
            s_edge[e * 64 + o] = v;
        }
        // key[o] from self_info = seqs[.,.,1,1] (e==4 -> offset 24)
        float key = bkr;
        #pragma unroll
        for (int r = 0; r < 6; ++r) key = fmaf(s_seq[24 + r], wk[r], key);
        __syncthreads();

        float vv[9], att[9];
        #pragma unroll
        for (int e = 0; e < 9; ++e) {
            const float4* ep = (const float4*)&s_edge[e * 64];
            float q0 = 0.f, q1 = 0.f, v0 = 0.f, v1 = 0.f;
            #pragma unroll
            for (int kk = 0; kk < 16; kk += 2) {
                float4 a = ep[kk];
                q0 = fmaf(a.x, wq[kk*4+0], q0);
                q0 = fmaf(a.y, wq[kk*4+1], q0);
                q0 = fmaf(a.z, wq[kk*4+2], q0);
                q0 = fmaf(a.w, wq[kk*4+3], q0);
                v0 = fmaf(a.x, wv[kk*4+0], v0);
                v0 = fmaf(a.y, wv[kk*4+1], v0);
                v0 = fmaf(a.z, wv[kk*4+2], v0);
                v0 = fmaf(a.w, wv[kk*4+3], v0);
                float4 b = ep[kk + 1];
                q1 = fmaf(b.x, wq[kk*4+4], q1);
                q1 = fmaf(b.y, wq[kk*4+5], q1);
                q1 = fmaf(b.z, wq[kk*4+6], q1);
                q1 = fmaf(b.w, wq[kk*4+7], q1);
                v1 = fmaf(b.x, wv[kk*4+4], v1);
                v1 = fmaf(b.y, wv[kk*4+5], v1);
                v1 = fmaf(b.z, wv[kk*4+6], v1);
                v1 = fmaf(b.w, wv[kk*4+7], v1);
            }
            float q = bqr + q0 + q1;
            vv[e] = bvr + v0 + v1;
            // per-head dot over the 16 lanes of this head
            float a_ = key * q;
            a_ += __shfl_xor(a_, 8, 16);
            a_ += __shfl_xor(a_, 4, 16);
            a_ += __shfl_xor(a_, 2, 16);
            a_ += __shfl_xor(a_, 1, 16);
            att[e] = a_ * 0.25f;   // / sqrt(16)
        }

        // masked softmax over e (all-masked row -> uniform 1/9, same as jax)
        float mx = -3.0e38f;
        #pragma unroll
        for (int e = 0; e < 9; ++e) {
            att[e] = (s_mask[e] == 0) ? -1.0e10f : att[e];
            mx = fmaxf(mx, att[e]);
        }
        float ssum = 0.f;
        #pragma unroll
        for (int e = 0; e < 9; ++e) { att[e] = __expf(att[e] - mx); ssum += att[e]; }
        float inv = 1.f / ssum;
        float acc = 0.f;
        #pragma unroll
        for (int e = 0; e < 9; ++e) acc = fmaf(att[e], vv[e], acc);
        ctx[p * 64 + o] = acc * inv;
        __syncthreads();
    }
}

// ---------------------------------------------------------------------------
// Kernel C: fused (x@W_ih + h@W_hh) LSTM over 50 steps + final projection.
// 256 blocks x 512 threads (= 1 block/CU); block owns 8 batch rows; thread j
// holds W_ih[j][:] (64) + W_hh[j][:] (128) in VGPRs for the whole sequence.
// __launch_bounds__(512, 1): an 8-wave block needs 2 waves/SIMD -> 256-VGPR
// cap. (512,2) capped at 128 VGPRs and spilled the weight arrays -> 6.9 GB
// of scratch traffic per dispatch (R1 counters). Do not raise arg 2.
// ---------------------------------------------------------------------------
__global__ __launch_bounds__(512, 1) void lstm_out(
    const float* __restrict__ ctx,    // [BS,SEQ,64]
    const float* __restrict__ W_ih,   // [512,64]
    const float* __restrict__ W_hh,   // [512,128]
    const float* __restrict__ b_ih, const float* __restrict__ b_hh,
    const float* __restrict__ W_out,  // [64,128]
    const float* __restrict__ b_out,  // [64]
    float* __restrict__ out)          // [BS,64]
{
    const int j    = threadIdx.x;       // gate index 0..511
    const int row0 = blockIdx.x * 8;
    const int r2   = j >> 6;            // phase-2 row 0..7
    const int m    = j & 63;            // phase-2 elem 0..63 (and m+64)

    float wih[64], whh[128];
    {
        const float4* ip = (const float4*)&W_ih[j * 64];
        #pragma unroll
        for (int k = 0; k < 16; ++k) {
            float4 a = ip[k];
            wih[k*4+0] = a.x; wih[k*4+1] = a.y; wih[k*4+2] = a.z; wih[k*4+3] = a.w;
        }
        const float4* hp = (const float4*)&W_hh[j * 128];
        #pragma unroll
        for (int k = 0; k < 32; ++k) {
            float4 a = hp[k];
            whh[k*4+0] = a.x; whh[k*4+1] = a.y; whh[k*4+2] = a.z; whh[k*4+3] = a.w;
        }
    }
    const float bias = b_ih[j] + b_hh[j];

    __shared__ float s_x[8][64];    // staged ctx slice
    __shared__ float s_h[8][128];   // hidden state
    __shared__ float s_g[8][512];   // pre-activation gates

    float c0 = 0.f, c1 = 0.f;       // cell state for (r2,m) and (r2,m+64)

    for (int s = 0; s < SEQ; ++s) {
        // stage x for this step (coalesced: 64 consecutive floats per row)
        s_x[r2][m] = ctx[((row0 + r2) * SEQ + s) * 64 + m];
        __syncthreads();

        float acc[8];
        #pragma unroll
        for (int r = 0; r < 8; ++r) acc[r] = bias;

        #pragma unroll
        for (int r = 0; r < 8; ++r) {
            const float4* xp = (const float4*)&s_x[r][0];
            #pragma unroll
            for (int kk = 0; kk < 16; ++kk) {
                float4 a = xp[kk];
                acc[r] = fmaf(a.x, wih[kk*4+0], acc[r]);
                acc[r] = fmaf(a.y, wih[kk*4+1], acc[r]);
                acc[r] = fmaf(a.z, wih[kk*4+2], acc[r]);
                acc[r] = fmaf(a.w, wih[kk*4+3], acc[r]);
            }
        }
        if (s > 0) {
            #pragma unroll
            for (int r = 0; r < 8; ++r) {
                const float4* hp = (const float4*)&s_h[r][0];
                #pragma unroll
                for (int kk = 0; kk < 32; ++kk) {
                    float4 a = hp[kk];
                    acc[r] = fmaf(a.x, whh[kk*4+0], acc[r]);
                    acc[r] = fmaf(a.y, whh[kk*4+1], acc[r]);
                    acc[r] = fmaf(a.z, whh[kk*4+2], acc[r]);
                    acc[r] = fmaf(a.w, whh[kk*4+3], acc[r]);
                }
            }
        }
        #pragma unroll
        for (int r = 0; r < 8; ++r) s_g[r][j] = acc[r];
        __syncthreads();

        // pointwise: i,f,g,o -> c,h for (r2,m) and (r2,m+64)
        {
            float i0 = sigf(s_g[r2][m]);
            float f0 = sigf(s_g[r2][128 + m]);
            float g0 = tanhfast(s_g[r2][256 + m]);
            float o0 = sigf(s_g[r2][384 + m]);
            c0 = fmaf(f0, c0, i0 * g0);
            s_h[r2][m] = o0 * tanhfast(c0);

            float i1 = sigf(s_g[r2][64 + m]);
            float f1 = sigf(s_g[r2][192 + m]);
            float g1 = tanhfast(s_g[r2][320 + m]);
            float o1 = sigf(s_g[r2][448 + m]);
            c1 = fmaf(f1, c1, i1 * g1);
            s_h[r2][m + 64] = o1 * tanhfast(c1);
        }
        __syncthreads();
    }

    // final projection: out[row0+r2][m] = b_out[m] + h . W_out[m]
    float acco = b_out[m];
    {
        const float4* hp = (const float4*)&s_h[r2][0];
        const float4* wp = (const float4*)&W_out[m * 128];
        #pragma unroll
        for (int kk = 0; kk < 32; ++kk) {
            float4 h4 = hp[kk];
            float4 w4 = wp[kk];
            acco = fmaf(h4.x, w4.x, acco);
            acco = fmaf(h4.y, w4.y, acco);
            acco = fmaf(h4.z, w4.z, acco);
            acco = fmaf(h4.w, w4.w, acco);
        }
    }
    out[(row0 + r2) * 64 + m] = acco;
}

// ---------------------------------------------------------------------------
extern "C" void kernel_launch(void* const* d_in, const int* in_sizes, int n_in,
                              void* d_out, int out_size, void* d_ws, size_t ws_size,
                              hipStream_t stream) {
    (void)in_sizes; (void)n_in; (void)out_size; (void)ws_size;
    const float* seqs  = (const float*)d_in[0];
    const float* ets   = (const float*)d_in[1];
    const int*   masks = (const int*)d_in[2];
    const float* Wf  = (const float*)d_in[3];
    const float* bf  = (const float*)d_in[4];
    const float* Wk  = (const float*)d_in[5];
    const float* bk  = (const float*)d_in[6];
    const float* Wq  = (const float*)d_in[7];
    const float* bq  = (const float*)d_in[8];
    const float* Wv  = (const float*)d_in[9];
    const float* bv  = (const float*)d_in[10];
    const float* Wih = (const float*)d_in[11];
    const float* Whh = (const float*)d_in[12];
    const float* bih = (const float*)d_in[13];
    const float* bhh = (const float*)d_in[14];
    const float* Wo  = (const float*)d_in[15];
    const float* bo  = (const float*)d_in[16];

    float* ctx = (float*)d_ws;  // [BS,SEQ,64] fp32 = 26.2 MB

    hipLaunchKernelGGL(edge_attn_ctx, dim3(4096), dim3(64), 0, stream,
                       seqs, ets, masks, Wf, bf, Wk, bk, Wq, bq, Wv, bv, ctx);
    hipLaunchKernelGGL(lstm_out, dim3(256), dim3(512), 0, stream,
                       ctx, Wih, Whh, bih, bhh, Wo, bo, (float*)d_out);
}

// Round 3
// 2433.435 us; speedup vs baseline: 1.3151x; 1.3151x over previous
//
#include <hip/hip_runtime.h>
#include <math.h>

#define BS   2048
#define SEQ  50
#define NPOS (BS * SEQ)

__device__ __forceinline__ float sigf(float x) { return 1.0f / (1.0f + __expf(-x)); }
__device__ __forceinline__ float tanhfast(float x) {
    float e = __expf(2.0f * x);
    return 1.0f - 2.0f / (e + 1.0f);
}

// ---- macro toolkit: named-SSA weight residency (NO private arrays — LLVM
// refuses to promote >~256B allocas to VGPRs; R1/R2 showed 6.4 GB of scratch
// re-read traffic from exactly that) --------------------------------------
#define FMA4(A, X, W) \
    A = fmaf((X).x, (W).x, A); A = fmaf((X).y, (W).y, A); \
    A = fmaf((X).z, (W).z, A); A = fmaf((X).w, (W).w, A);

#define LD16(P, N) \
    float4 N##0=(P)[0],  N##1=(P)[1],  N##2=(P)[2],  N##3=(P)[3], \
           N##4=(P)[4],  N##5=(P)[5],  N##6=(P)[6],  N##7=(P)[7], \
           N##8=(P)[8],  N##9=(P)[9],  N##10=(P)[10],N##11=(P)[11], \
           N##12=(P)[12],N##13=(P)[13],N##14=(P)[14],N##15=(P)[15];

#define LD32(P, N) LD16(P, N) \
    float4 N##16=(P)[16],N##17=(P)[17],N##18=(P)[18],N##19=(P)[19], \
           N##20=(P)[20],N##21=(P)[21],N##22=(P)[22],N##23=(P)[23], \
           N##24=(P)[24],N##25=(P)[25],N##26=(P)[26],N##27=(P)[27], \
           N##28=(P)[28],N##29=(P)[29],N##30=(P)[30],N##31=(P)[31];

#define DOT16(A, X, W) \
    FMA4(A,(X)[0],W##0)   FMA4(A,(X)[1],W##1)   FMA4(A,(X)[2],W##2)   FMA4(A,(X)[3],W##3) \
    FMA4(A,(X)[4],W##4)   FMA4(A,(X)[5],W##5)   FMA4(A,(X)[6],W##6)   FMA4(A,(X)[7],W##7) \
    FMA4(A,(X)[8],W##8)   FMA4(A,(X)[9],W##9)   FMA4(A,(X)[10],W##10) FMA4(A,(X)[11],W##11) \
    FMA4(A,(X)[12],W##12) FMA4(A,(X)[13],W##13) FMA4(A,(X)[14],W##14) FMA4(A,(X)[15],W##15)

#define DOT32(A, X, W) DOT16(A, X, W) \
    FMA4(A,(X)[16],W##16) FMA4(A,(X)[17],W##17) FMA4(A,(X)[18],W##18) FMA4(A,(X)[19],W##19) \
    FMA4(A,(X)[20],W##20) FMA4(A,(X)[21],W##21) FMA4(A,(X)[22],W##22) FMA4(A,(X)[23],W##23) \
    FMA4(A,(X)[24],W##24) FMA4(A,(X)[25],W##25) FMA4(A,(X)[26],W##26) FMA4(A,(X)[27],W##27) \
    FMA4(A,(X)[28],W##28) FMA4(A,(X)[29],W##29) FMA4(A,(X)[30],W##30) FMA4(A,(X)[31],W##31)

// ---------------------------------------------------------------------------
// Kernel A: edge fusion + masked multi-head attention -> ctx[BS][SEQ][64]
// block = 64 threads (1 wave); lane = output channel o; Wq/Wv rows as named
// SSA float4s (32 regs x4 = 128 VGPR).
// ---------------------------------------------------------------------------
__global__ __launch_bounds__(64, 1) void edge_attn_ctx(
    const float* __restrict__ seqs,   // [BS,SEQ,3,3,6]
    const float* __restrict__ ets,    // [BS,SEQ,3,3,4]
    const int*   __restrict__ masks,  // [BS,SEQ,3,3]
    const float* __restrict__ Wf, const float* __restrict__ bf,  // [64,19],[64]
    const float* __restrict__ Wk, const float* __restrict__ bk,  // [64,6],[64]
    const float* __restrict__ Wq, const float* __restrict__ bq,  // [64,64],[64]
    const float* __restrict__ Wv, const float* __restrict__ bv,  // [64,64],[64]
    float* __restrict__ ctx)          // [BS,SEQ,64]
{
    const int o = threadIdx.x;

    const float4* qp = (const float4*)&Wq[o * 64];
    LD16(qp, wq)
    const float4* vp = (const float4*)&Wv[o * 64];
    LD16(vp, wv)

    // small weight rows as named scalars (avoid any alloca)
    const float* wfp = &Wf[o * 19];
    float wf0=wfp[0], wf1=wfp[1], wf2=wfp[2], wf3=wfp[3], wf4=wfp[4], wf5=wfp[5],
          wf6=wfp[6], wf7=wfp[7], wf8=wfp[8], wf9=wfp[9];
    float wfe0=wfp[10], wfe1=wfp[11], wfe2=wfp[12], wfe3=wfp[13], wfe4=wfp[14],
          wfe5=wfp[15], wfe6=wfp[16], wfe7=wfp[17], wfe8=wfp[18];
    const float* wkp = &Wk[o * 6];
    float wk0=wkp[0], wk1=wkp[1], wk2=wkp[2], wk3=wkp[3], wk4=wkp[4], wk5=wkp[5];

    const float bfr = bf[o], bkr = bk[o], bqr = bq[o], bvr = bv[o];

    __shared__ float s_seq[54];
    __shared__ float s_et[36];
    __shared__ int   s_mask[9];
    __shared__ float s_edge[9 * 64];

    for (int p = blockIdx.x; p < NPOS; p += gridDim.x) {
        if (o < 54) s_seq[o]  = seqs[p * 54 + o];
        if (o < 36) s_et[o]   = ets[p * 36 + o];
        if (o < 9)  s_mask[o] = masks[p * 9 + o];
        __syncthreads();

        // edge_info[e][o]: fused 19-dot; eye(9) concat collapses to wfe[e].
        float wfe[9] = {wfe0,wfe1,wfe2,wfe3,wfe4,wfe5,wfe6,wfe7,wfe8}; // const-idx, unrolled below
        #pragma unroll
        for (int e = 0; e < 9; ++e) {
            float v = bfr + wfe[e];
            v = fmaf(s_seq[e*6+0], wf0, v);
            v = fmaf(s_seq[e*6+1], wf1, v);
            v = fmaf(s_seq[e*6+2], wf2, v);
            v = fmaf(s_seq[e*6+3], wf3, v);
            v = fmaf(s_seq[e*6+4], wf4, v);
            v = fmaf(s_seq[e*6+5], wf5, v);
            v = fmaf(s_et[e*4+0],  wf6, v);
            v = fmaf(s_et[e*4+1],  wf7, v);
            v = fmaf(s_et[e*4+2],  wf8, v);
            v = fmaf(s_et[e*4+3],  wf9, v);
            s_edge[e * 64 + o] = v;
        }
        // key[o] from self_info = seqs[.,.,1,1] (e==4 -> offset 24)
        float key = bkr;
        key = fmaf(s_seq[24], wk0, key);
        key = fmaf(s_seq[25], wk1, key);
        key = fmaf(s_seq[26], wk2, key);
        key = fmaf(s_seq[27], wk3, key);
        key = fmaf(s_seq[28], wk4, key);
        key = fmaf(s_seq[29], wk5, key);
        __syncthreads();

        float vv[9], att[9];   // 36 B each, const-indexed — SROA-safe
        #pragma unroll
        for (int e = 0; e < 9; ++e) {
            const float4* ep = (const float4*)&s_edge[e * 64];
            float q = 0.f, v = 0.f;
            {
                float4 t;
                t=ep[0];  FMA4(q,t,wq0)  FMA4(v,t,wv0)
                t=ep[1];  FMA4(q,t,wq1)  FMA4(v,t,wv1)
                t=ep[2];  FMA4(q,t,wq2)  FMA4(v,t,wv2)
                t=ep[3];  FMA4(q,t,wq3)  FMA4(v,t,wv3)
                t=ep[4];  FMA4(q,t,wq4)  FMA4(v,t,wv4)
                t=ep[5];  FMA4(q,t,wq5)  FMA4(v,t,wv5)
                t=ep[6];  FMA4(q,t,wq6)  FMA4(v,t,wv6)
                t=ep[7];  FMA4(q,t,wq7)  FMA4(v,t,wv7)
                t=ep[8];  FMA4(q,t,wq8)  FMA4(v,t,wv8)
                t=ep[9];  FMA4(q,t,wq9)  FMA4(v,t,wv9)
                t=ep[10]; FMA4(q,t,wq10) FMA4(v,t,wv10)
                t=ep[11]; FMA4(q,t,wq11) FMA4(v,t,wv11)
                t=ep[12]; FMA4(q,t,wq12) FMA4(v,t,wv12)
                t=ep[13]; FMA4(q,t,wq13) FMA4(v,t,wv13)
                t=ep[14]; FMA4(q,t,wq14) FMA4(v,t,wv14)
                t=ep[15]; FMA4(q,t,wq15) FMA4(v,t,wv15)
            }
            float qq = bqr + q;
            vv[e] = bvr + v;
            // per-head dot over the 16 lanes of this head
            float a_ = key * qq;
            a_ += __shfl_xor(a_, 8, 16);
            a_ += __shfl_xor(a_, 4, 16);
            a_ += __shfl_xor(a_, 2, 16);
            a_ += __shfl_xor(a_, 1, 16);
            att[e] = a_ * 0.25f;   // / sqrt(16)
        }

        // masked softmax over e (all-masked row -> uniform 1/9, same as jax)
        float mx = -3.0e38f;
        #pragma unroll
        for (int e = 0; e < 9; ++e) {
            att[e] = (s_mask[e] == 0) ? -1.0e10f : att[e];
            mx = fmaxf(mx, att[e]);
        }
        float ssum = 0.f;
        #pragma unroll
        for (int e = 0; e < 9; ++e) { att[e] = __expf(att[e] - mx); ssum += att[e]; }
        float inv = 1.f / ssum;
        float acc = 0.f;
        #pragma unroll
        for (int e = 0; e < 9; ++e) acc = fmaf(att[e], vv[e], acc);
        ctx[p * 64 + o] = acc * inv;
        __syncthreads();
    }
}

// ---------------------------------------------------------------------------
// Kernel C: fused (x@W_ih + h@W_hh) LSTM over 50 steps + final projection.
// 256 blocks x 512 threads (1 block/CU); thread j holds W_ih[j][:] + W_hh[j][:]
// as 48 named float4 SSA values (192 VGPR) — no allocas, no scratch.
// ---------------------------------------------------------------------------
#define XP(r) ((const float4*)&s_x[r][0])
#define HP(r) ((const float4*)&s_h[r][0])

__global__ __launch_bounds__(512, 1) void lstm_out(
    const float* __restrict__ ctx,    // [BS,SEQ,64]
    const float* __restrict__ W_ih,   // [512,64]
    const float* __restrict__ W_hh,   // [512,128]
    const float* __restrict__ b_ih, const float* __restrict__ b_hh,
    const float* __restrict__ W_out,  // [64,128]
    const float* __restrict__ b_out,  // [64]
    float* __restrict__ out)          // [BS,64]
{
    const int j    = threadIdx.x;       // gate index 0..511
    const int row0 = blockIdx.x * 8;
    const int r2   = j >> 6;            // phase-2 row 0..7
    const int m    = j & 63;            // phase-2 elem 0..63 (and m+64)

    const float4* ip = (const float4*)&W_ih[j * 64];
    LD16(ip, wi)
    const float4* hp = (const float4*)&W_hh[j * 128];
    LD32(hp, wh)

    const float bias = b_ih[j] + b_hh[j];

    __shared__ float s_x[8][64];    // staged ctx slice
    __shared__ float s_h[8][128];   // hidden state
    __shared__ float s_g[8][512];   // pre-activation gates

    float c0 = 0.f, c1 = 0.f;       // cell state for (r2,m) and (r2,m+64)

    for (int s = 0; s < SEQ; ++s) {
        // stage x for this step (coalesced: 64 consecutive floats per row)
        s_x[r2][m] = ctx[((row0 + r2) * SEQ + s) * 64 + m];
        __syncthreads();

        float a0=bias, a1=bias, a2=bias, a3=bias, a4=bias, a5=bias, a6=bias, a7=bias;

        DOT16(a0, XP(0), wi)
        DOT16(a1, XP(1), wi)
        DOT16(a2, XP(2), wi)
        DOT16(a3, XP(3), wi)
        DOT16(a4, XP(4), wi)
        DOT16(a5, XP(5), wi)
        DOT16(a6, XP(6), wi)
        DOT16(a7, XP(7), wi)

        if (s > 0) {
            DOT32(a0, HP(0), wh)
            DOT32(a1, HP(1), wh)
            DOT32(a2, HP(2), wh)
            DOT32(a3, HP(3), wh)
            DOT32(a4, HP(4), wh)
            DOT32(a5, HP(5), wh)
            DOT32(a6, HP(6), wh)
            DOT32(a7, HP(7), wh)
        }
        s_g[0][j]=a0; s_g[1][j]=a1; s_g[2][j]=a2; s_g[3][j]=a3;
        s_g[4][j]=a4; s_g[5][j]=a5; s_g[6][j]=a6; s_g[7][j]=a7;
        __syncthreads();

        // pointwise: i,f,g,o -> c,h for (r2,m) and (r2,m+64)
        {
            float i0 = sigf(s_g[r2][m]);
            float f0 = sigf(s_g[r2][128 + m]);
            float g0 = tanhfast(s_g[r2][256 + m]);
            float o0 = sigf(s_g[r2][384 + m]);
            c0 = fmaf(f0, c0, i0 * g0);
            s_h[r2][m] = o0 * tanhfast(c0);

            float i1 = sigf(s_g[r2][64 + m]);
            float f1 = sigf(s_g[r2][192 + m]);
            float g1 = tanhfast(s_g[r2][320 + m]);
            float o1 = sigf(s_g[r2][448 + m]);
            c1 = fmaf(f1, c1, i1 * g1);
            s_h[r2][m + 64] = o1 * tanhfast(c1);
        }
        __syncthreads();
    }

    // final projection: out[row0+r2][m] = b_out[m] + h . W_out[m]
    float acco = b_out[m];
    {
        const float4* hq = (const float4*)&s_h[r2][0];
        const float4* wp = (const float4*)&W_out[m * 128];
        #pragma unroll
        for (int kk = 0; kk < 32; ++kk) {
            float4 h4 = hq[kk];
            float4 w4 = wp[kk];
            acco = fmaf(h4.x, w4.x, acco);
            acco = fmaf(h4.y, w4.y, acco);
            acco = fmaf(h4.z, w4.z, acco);
            acco = fmaf(h4.w, w4.w, acco);
        }
    }
    out[(row0 + r2) * 64 + m] = acco;
}

// ---------------------------------------------------------------------------
extern "C" void kernel_launch(void* const* d_in, const int* in_sizes, int n_in,
                              void* d_out, int out_size, void* d_ws, size_t ws_size,
                              hipStream_t stream) {
    (void)in_sizes; (void)n_in; (void)out_size; (void)ws_size;
    const float* seqs  = (const float*)d_in[0];
    const float* ets   = (const float*)d_in[1];
    const int*   masks = (const int*)d_in[2];
    const float* Wf  = (const float*)d_in[3];
    const float* bf  = (const float*)d_in[4];
    const float* Wk  = (const float*)d_in[5];
    const float* bk  = (const float*)d_in[6];
    const float* Wq  = (const float*)d_in[7];
    const float* bq  = (const float*)d_in[8];
    const float* Wv  = (const float*)d_in[9];
    const float* bv  = (const float*)d_in[10];
    const float* Wih = (const float*)d_in[11];
    const float* Whh = (const float*)d_in[12];
    const float* bih = (const float*)d_in[13];
    const float* bhh = (const float*)d_in[14];
    const float* Wo  = (const float*)d_in[15];
    const float* bo  = (const float*)d_in[16];

    float* ctx = (float*)d_ws;  // [BS,SEQ,64] fp32 = 26.2 MB

    hipLaunchKernelGGL(edge_attn_ctx, dim3(4096), dim3(64), 0, stream,
                       seqs, ets, masks, Wf, bf, Wk, bk, Wq, bq, Wv, bv, ctx);
    hipLaunchKernelGGL(lstm_out, dim3(256), dim3(512), 0, stream,
                       ctx, Wih, Whh, bih, bhh, Wo, bo, (float*)d_out);
}